// Round 1
// baseline (159.232 us; speedup 1.0000x reference)
//
#include <hip/hip_runtime.h>
#include <hip/hip_bf16.h>

#define B_DIM 8
#define T_DIM 2048
#define C_DIM 1024
#define H_DIM 64
#define BT (B_DIM * T_DIM)

typedef __attribute__((ext_vector_type(8))) short bf16x8;
typedef __attribute__((ext_vector_type(4))) float f32x4;

__device__ __forceinline__ ushort f2bf(float f) {
    __hip_bfloat16 h = __float2bfloat16(f);
    return *reinterpret_cast<ushort*>(&h);
}
__device__ __forceinline__ unsigned int packbf(float a, float b) {
    return (unsigned int)f2bf(a) | ((unsigned int)f2bf(b) << 16);
}

// ---------------------------------------------------------------------------
// Wt[n][k] = W(sel)[k][n&63]; n<64: Wk, n<128: Wq (pre-scaled by 0.125*log2e
// so attention runs in exp2 domain), else Wv. bf16.
// v2: coalesced via LDS transpose. grid = 3 mats x 16 k-chunks = 48 blocks.
// Reads 64x64 f32 tiles with 256B-contiguous rows; writes packed uint4.
// ---------------------------------------------------------------------------
__global__ __launch_bounds__(256) void wt_convert_kernel(
    const float* __restrict__ Wk, const float* __restrict__ Wq,
    const float* __restrict__ Wv, ushort* __restrict__ wt)
{
    __shared__ float tile[64][65];
    const int mat = blockIdx.x >> 4;
    const int k0 = (blockIdx.x & 15) << 6;
    const float* src = (mat == 0) ? Wk : (mat == 1) ? Wq : Wv;
    const float scale = (mat == 1) ? 0.125f * 1.4426950408889634f : 1.0f;
    #pragma unroll
    for (int i = 0; i < 16; ++i) {
        const int idx = i * 256 + threadIdx.x;
        const int r = idx >> 6, c = idx & 63;          // consecutive lanes -> consecutive c
        tile[r][c] = src[(size_t)(k0 + r) * H_DIM + c];
    }
    __syncthreads();
    // thread t writes wt[mat*64 + (t>>2)][k0 + (t&3)*16 .. +16] (32B contiguous)
    const int c = threadIdx.x >> 2, r0 = (threadIdx.x & 3) << 4;
    unsigned int u[8];
    #pragma unroll
    for (int j = 0; j < 8; ++j)
        u[j] = packbf(tile[r0 + 2 * j][c] * scale, tile[r0 + 2 * j + 1][c] * scale);
    ushort* dst = wt + (size_t)(mat * 64 + c) * C_DIM + k0 + r0;
    *(uint4*)(dst)     = (uint4){u[0], u[1], u[2], u[3]};
    *(uint4*)(dst + 8) = (uint4){u[4], u[5], u[6], u[7]};
}

// ---------------------------------------------------------------------------
// QKV GEMM v4: M=32/block, 512 blocks x 4 waves. Key observation: each W
// fragment region (nt*2+ks) is consumed by exactly ONE wave -> W goes
// global->VGPR directly (no LDS round-trip), register-double-buffered one
// 64-k slab ahead. Only x is cross-wave shared: staged f32->bf16 into
// double-buffered LDS (wave w owns region w), one barrier/iter.
// Outputs k,q row-major bf16 and V^T [batch][64][2048] bf16.  (unchanged)
// ---------------------------------------------------------------------------
__global__ __launch_bounds__(256) void qkv_gemm_kernel(
    const float* __restrict__ x, const ushort* __restrict__ wt,
    ushort* __restrict__ kb, ushort* __restrict__ qb, ushort* __restrict__ vt)
{
    __shared__ ushort Xf[2][4 * 64 * 8];     // 8 KB [buf][mf*2+ks][lane][8]
    const int tid = threadIdx.x;
    const int wave = tid >> 6, lane = tid & 63;
    const int col = lane & 15, quad = lane >> 4;
    const int r0 = blockIdx.x * 32;

    f32x4 acc[2][3];
    #pragma unroll
    for (int m = 0; m < 2; ++m)
        #pragma unroll
        for (int i = 0; i < 3; ++i) acc[m][i] = (f32x4){0.f, 0.f, 0.f, 0.f};

    // X staging: wave w owns region w (mf=w>>1, ks=w&1)
    const int xrow = (wave >> 1) * 16 + col;
    const int xcc  = (wave & 1) * 4 + quad;
    const float* xsrc = x + (size_t)(r0 + xrow) * C_DIM + xcc * 8;

    // W fragments for THIS wave: n-tiles wave*3+j, ksteps ks
    const ushort* wsrc[3][2];
    #pragma unroll
    for (int j = 0; j < 3; ++j)
        #pragma unroll
        for (int ks = 0; ks < 2; ++ks)
            wsrc[j][ks] = wt + (size_t)((wave * 3 + j) * 16 + col) * C_DIM
                             + ks * 32 + quad * 8;

    // ---- prologue: slab 0 -> x LDS buf0, W regs ----
    {
        const float4 f0 = *(const float4*)(xsrc);
        const float4 f1 = *(const float4*)(xsrc + 4);
        uint4 u;
        u.x = packbf(f0.x, f0.y); u.y = packbf(f0.z, f0.w);
        u.z = packbf(f1.x, f1.y); u.w = packbf(f1.z, f1.w);
        *(uint4*)&Xf[0][(wave * 64 + lane) * 8] = u;
    }
    bf16x8 wcur[3][2];
    #pragma unroll
    for (int j = 0; j < 3; ++j)
        #pragma unroll
        for (int ks = 0; ks < 2; ++ks)
            wcur[j][ks] = *(const bf16x8*)(wsrc[j][ks]);
    __syncthreads();

    for (int i = 0; i < 16; ++i) {
        const int b = i & 1;
        bf16x8 wnxt[3][2];
        float4 nf0, nf1;
        if (i < 15) {   // issue next-slab loads before the MFMA block
            const int k1 = (i + 1) * 64;
            #pragma unroll
            for (int j = 0; j < 3; ++j)
                #pragma unroll
                for (int ks = 0; ks < 2; ++ks)
                    wnxt[j][ks] = *(const bf16x8*)(wsrc[j][ks] + k1);
            nf0 = *(const float4*)(xsrc + k1);
            nf1 = *(const float4*)(xsrc + k1 + 4);
        }
        // ---- compute slab i: x frags from LDS buf b, W from regs ----
        #pragma unroll
        for (int ks = 0; ks < 2; ++ks) {
            const bf16x8 a0 = *(const bf16x8*)&Xf[b][((    ks) * 64 + lane) * 8];
            const bf16x8 a1 = *(const bf16x8*)&Xf[b][((2 + ks) * 64 + lane) * 8];
            #pragma unroll
            for (int j = 0; j < 3; ++j) {
                acc[0][j] = __builtin_amdgcn_mfma_f32_16x16x32_bf16(a0, wcur[j][ks], acc[0][j], 0, 0, 0);
                acc[1][j] = __builtin_amdgcn_mfma_f32_16x16x32_bf16(a1, wcur[j][ks], acc[1][j], 0, 0, 0);
            }
        }
        if (i < 15) {   // rotate W regs, write next x slab to other buffer
            #pragma unroll
            for (int j = 0; j < 3; ++j)
                #pragma unroll
                for (int ks = 0; ks < 2; ++ks)
                    wcur[j][ks] = wnxt[j][ks];
            uint4 u;
            u.x = packbf(nf0.x, nf0.y); u.y = packbf(nf0.z, nf0.w);
            u.z = packbf(nf1.x, nf1.y); u.w = packbf(nf1.z, nf1.w);
            *(uint4*)&Xf[b ^ 1][(wave * 64 + lane) * 8] = u;
        }
        __syncthreads();
    }

    // epilogue: C layout col=lane&15, row=quad*4+reg (+ mf*16)
    #pragma unroll
    for (int i = 0; i < 3; ++i) {
        const int nt = wave * 3 + i;
        #pragma unroll
        for (int mf = 0; mf < 2; ++mf) {
            const int rbase = r0 + mf * 16 + quad * 4;
            if (nt < 4) {
                const int n = nt * 16 + col;
                #pragma unroll
                for (int r = 0; r < 4; ++r)
                    kb[(size_t)(rbase + r) * H_DIM + n] = f2bf(acc[mf][i][r]);
            } else if (nt < 8) {
                const int n = nt * 16 + col - 64;
                #pragma unroll
                for (int r = 0; r < 4; ++r)
                    qb[(size_t)(rbase + r) * H_DIM + n] = f2bf(acc[mf][i][r]);
            } else {
                const int h = nt * 16 + col - 128;
                const int vbatch = rbase >> 11, vrow = rbase & (T_DIM - 1);
                ushort u4[4] = {f2bf(acc[mf][i][0]), f2bf(acc[mf][i][1]),
                                f2bf(acc[mf][i][2]), f2bf(acc[mf][i][3])};
                unsigned long long uu; __builtin_memcpy(&uu, u4, 8);
                *(unsigned long long*)(vt + ((size_t)vbatch * H_DIM + h) * T_DIM + vrow) = uu;
            }
        }
    }
}

// ---------------------------------------------------------------------------
// MFMA flash attention v3 (S^T formulation). grid = 8 batches x 128 q-tiles
// (batch = bid&7 for XCD/L2 affinity, big q-tiles first). 4 waves key-split
// (t = w mod 4) with private scalar m,l and O^T acc; one end-merge barrier.
// S^T = K Q^T: lane owns ONE q-column -> softmax is in-lane + 2 shfl rounds.
// v3 changes vs v2:
//   * s_setprio(1) around both MFMA clusters (T5: +4-7% measured on attn).
//   * deferred rescale, THR=8 in exp2 domain (T13): skip the 16 o_-muls +
//     corr-exp unless the tile max grew past m_+8; wave-uniform via __any.
//     P bounded by 2^8; l_/O^T scale-invariant in the end merge.
//   * tree-shaped max/sum reductions (depth 4/3 instead of serial 15-chains).
//   * raw v_exp_f32 via __builtin_amdgcn_exp2f (no ocml edge-case chain).
// ---------------------------------------------------------------------------
__global__ __launch_bounds__(256) void attn_kernel(
    const ushort* __restrict__ kb, const ushort* __restrict__ qb,
    const ushort* __restrict__ vt, float* __restrict__ out)
{
    __shared__ unsigned int Ps[4][16 * 34];  // per-wave P^T pairs, stride 34
    __shared__ float Om[4][64][17];          // wave partial O^T [h][q]
    __shared__ float Mm[4][16], Lm[4][16];

    const int tid = threadIdx.x;
    const int wave = tid >> 6, lane = tid & 63;
    const int col = lane & 15, quad = lane >> 4;  // col = q (and A-frag m-row)
    const int batch = blockIdx.x & 7;
    const int qtile = 127 - (blockIdx.x >> 3);
    const int q0 = qtile * 16;

    const ushort* kbase = kb + (size_t)batch * T_DIM * H_DIM;
    const ushort* vbase = vt + (size_t)batch * H_DIM * T_DIM;

    // Q B-frags: lane n=col reads Q row q0+col, h = ks*32 + quad*8 + j
    const size_t qoff = (size_t)(batch * T_DIM + q0 + col) * H_DIM + quad * 8;
    const bf16x8 bq0 = *(const bf16x8*)(qb + qoff);
    const bf16x8 bq1 = *(const bf16x8*)(qb + qoff + 32);

    float m_ = -INFINITY, l_ = 0.f;
    f32x4 o_[4];
    #pragma unroll
    for (int i = 0; i < 4; ++i) o_[i] = (f32x4){0.f, 0.f, 0.f, 0.f};

    const int ntiles = (q0 + 16 + 63) >> 6;
    unsigned int* psw = &Ps[wave][0];

    for (int t = wave; t < ntiles; t += 4) {
        const int kb0 = t * 64;
        // ---- S^T = K Q^T : A = K rows, B = Q rows ----
        f32x4 s[4];
        #pragma unroll
        for (int mt = 0; mt < 4; ++mt) s[mt] = (f32x4){0.f, 0.f, 0.f, 0.f};
        __builtin_amdgcn_s_setprio(1);
        #pragma unroll
        for (int ks = 0; ks < 2; ++ks) {
            const bf16x8 bq = ks ? bq1 : bq0;
            #pragma unroll
            for (int mt = 0; mt < 4; ++mt) {
                const bf16x8 ak = *(const bf16x8*)
                    (kbase + (size_t)(kb0 + mt * 16 + col) * H_DIM + ks * 32 + quad * 8);
                s[mt] = __builtin_amdgcn_mfma_f32_16x16x32_bf16(ak, bq, s[mt], 0, 0, 0);
            }
        }
        __builtin_amdgcn_s_setprio(0);
        // ---- causal mask (in-lane; key = kb0+mt*16+quad*4+reg, q = q0+col) ----
        if (kb0 + 63 > q0) {
            const int kq = kb0 + quad * 4 - q0 - col;
            #pragma unroll
            for (int mt = 0; mt < 4; ++mt)
                #pragma unroll
                for (int reg = 0; reg < 4; ++reg)
                    if (kq + mt * 16 + reg > 0) s[mt][reg] = -INFINITY;
        }
        // ---- tile max: tree reduce (depth 4) + 2 shfl rounds ----
        float mr;
        {
            const float a = fmaxf(s[0][0], s[0][1]), b = fmaxf(s[0][2], s[0][3]);
            const float c = fmaxf(s[1][0], s[1][1]), d = fmaxf(s[1][2], s[1][3]);
            const float e = fmaxf(s[2][0], s[2][1]), f = fmaxf(s[2][2], s[2][3]);
            const float g = fmaxf(s[3][0], s[3][1]), h = fmaxf(s[3][2], s[3][3]);
            mr = fmaxf(fmaxf(fmaxf(a, b), fmaxf(c, d)),
                       fmaxf(fmaxf(e, f), fmaxf(g, h)));
        }
        mr = fmaxf(mr, __shfl_xor(mr, 16));
        mr = fmaxf(mr, __shfl_xor(mr, 32));
        // ---- deferred rescale (T13): only when max grew past threshold ----
        if (__any(mr > m_ + 8.f)) {
            const float mn = fmaxf(m_, mr);
            const float corr = __builtin_amdgcn_exp2f(m_ - mn);  // 0 on first tile
            l_ *= corr;
            #pragma unroll
            for (int ht = 0; ht < 4; ++ht) o_[ht] *= corr;
            m_ = mn;
        }
        // ---- P = exp2(S - m_), tree-summed ----
        float psum[4];
        #pragma unroll
        for (int mt = 0; mt < 4; ++mt) {
            #pragma unroll
            for (int reg = 0; reg < 4; ++reg)
                s[mt][reg] = __builtin_amdgcn_exp2f(s[mt][reg] - m_);
            psum[mt] = (s[mt][0] + s[mt][1]) + (s[mt][2] + s[mt][3]);
        }
        float sum = (psum[0] + psum[1]) + (psum[2] + psum[3]);
        sum += __shfl_xor(sum, 16);
        sum += __shfl_xor(sum, 32);
        l_ += sum;
        // ---- P^T -> per-wave LDS, packed pairs along key (4 b64 writes) ----
        #pragma unroll
        for (int mt = 0; mt < 4; ++mt) {
            uint2 w2;
            w2.x = packbf(s[mt][0], s[mt][1]);
            w2.y = packbf(s[mt][2], s[mt][3]);
            *(uint2*)&psw[col * 34 + mt * 8 + quad * 2] = w2;
        }
        // ---- O^T += V^T P^T : A = V^T rows (direct), B = P rows from LDS ----
        __builtin_amdgcn_s_setprio(1);
        #pragma unroll
        for (int ks2 = 0; ks2 < 2; ++ks2) {
            const uint2 ra = *(const uint2*)&psw[col * 34 + ks2 * 16 + quad * 4];
            const uint2 rb = *(const uint2*)&psw[col * 34 + ks2 * 16 + quad * 4 + 2];
            unsigned int ub[4] = {ra.x, ra.y, rb.x, rb.y};
            bf16x8 bp; __builtin_memcpy(&bp, ub, 16);
            #pragma unroll
            for (int ht = 0; ht < 4; ++ht) {
                const bf16x8 av = *(const bf16x8*)
                    (vbase + (size_t)(ht * 16 + col) * T_DIM + kb0 + ks2 * 32 + quad * 8);
                o_[ht] = __builtin_amdgcn_mfma_f32_16x16x32_bf16(av, bp, o_[ht], 0, 0, 0);
            }
        }
        __builtin_amdgcn_s_setprio(0);
    }

    // ---- write wave partials (O^T: row h = ht*16+quad*4+reg, col q) ----
    #pragma unroll
    for (int ht = 0; ht < 4; ++ht)
        #pragma unroll
        for (int reg = 0; reg < 4; ++reg)
            Om[wave][ht * 16 + quad * 4 + reg][col] = o_[ht][reg];
    if (lane < 16) { Mm[wave][lane] = m_; Lm[wave][lane] = l_; }
    __syncthreads();
    // ---- merge 4 wave partials; idle waves (m=-inf,l=0,o=0) contribute 0 ----
    {
        const int q = tid >> 4, hb = tid & 15;
        const float M = fmaxf(fmaxf(Mm[0][q], Mm[1][q]), fmaxf(Mm[2][q], Mm[3][q]));
        const float a0 = __builtin_amdgcn_exp2f(Mm[0][q] - M);
        const float a1 = __builtin_amdgcn_exp2f(Mm[1][q] - M);
        const float a2 = __builtin_amdgcn_exp2f(Mm[2][q] - M);
        const float a3 = __builtin_amdgcn_exp2f(Mm[3][q] - M);
        const float L = Lm[0][q] * a0 + Lm[1][q] * a1 + Lm[2][q] * a2 + Lm[3][q] * a3;
        const float rL = 1.0f / L;
        float* orow = out + (size_t)(batch * T_DIM + q0 + q) * H_DIM;
        #pragma unroll
        for (int i = 0; i < 4; ++i) {
            const int h = hb + 16 * i;
            orow[h] = (Om[0][h][q] * a0 + Om[1][h][q] * a1 +
                       Om[2][h][q] * a2 + Om[3][h][q] * a3) * rL;
        }
    }
}

extern "C" void kernel_launch(void* const* d_in, const int* in_sizes, int n_in,
                              void* d_out, int out_size, void* d_ws, size_t ws_size,
                              hipStream_t stream)
{
    const float* x  = (const float*)d_in[0];
    const float* Wk = (const float*)d_in[1];
    const float* Wq = (const float*)d_in[2];
    const float* Wv = (const float*)d_in[3];

    ushort* kbuf = (ushort*)d_ws;                       // [BT][64] bf16
    ushort* qbuf = kbuf + (size_t)BT * H_DIM;           // [BT][64] bf16 (pre-scaled)
    ushort* vtb  = qbuf + (size_t)BT * H_DIM;           // V^T [8][64][2048] bf16
    ushort* wt   = vtb  + (size_t)BT * H_DIM;           // [192][1024] bf16

    wt_convert_kernel<<<48, 256, 0, stream>>>(Wk, Wq, Wv, wt);
    qkv_gemm_kernel<<<BT / 32, 256, 0, stream>>>(x, wt, kbuf, qbuf, vtb);
    attn_kernel<<<B_DIM * 128, 256, 0, stream>>>(kbuf, qbuf, vtb, (float*)d_out);
}